// Round 17
// baseline (251.413 us; speedup 1.0000x reference)
//
#include <hip/hip_runtime.h>

#define CH 128
#define N_REL 8
#define OUT_CH 16
#define NEG_SLOPE 0.2f

typedef short short8 __attribute__((ext_vector_type(8)));
typedef float f32x4 __attribute__((ext_vector_type(4)));
typedef float f32x2 __attribute__((ext_vector_type(2)));

// ---------- helpers ----------
__device__ __forceinline__ unsigned short f2bf(float f) {  // RTN-even f32->bf16
    unsigned u = __float_as_uint(f);
    return (unsigned short)((u + 0x7fffu + ((u >> 16) & 1u)) >> 16);
}

// ================= device bodies =================

__device__ __forceinline__ void dev_cast(const float* __restrict__ X,
                                         unsigned short* __restrict__ Xb,
                                         long total, int b, int tid) {
    long i = ((long)b * 256 + tid) * 8;
    if (i >= total) return;
    float4 v0 = *(const float4*)(X + i);
    float4 v1 = *(const float4*)(X + i + 4);
    ushort4 a, c;
    a.x = f2bf(v0.x); a.y = f2bf(v0.y); a.z = f2bf(v0.z); a.w = f2bf(v0.w);
    c.x = f2bf(v1.x); c.y = f2bf(v1.y); c.z = f2bf(v1.z); c.w = f2bf(v1.w);
    *(ushort4*)(Xb + i) = a;
    *(ushort4*)(Xb + i + 4) = c;
}

__device__ __forceinline__ void dev_wqk(const float* __restrict__ W,
                                        const float* __restrict__ qv,
                                        const float* __restrict__ kv,
                                        float* __restrict__ wq, float* __restrict__ wk,
                                        int rb, int tid) {
    int r = rb * 2 + (tid >> 7);
    int i = tid & 127;
    const float* row = W + ((size_t)r * CH + i) * CH;
    float aq = 0.f, ak = 0.f;
    for (int o = 0; o < CH; ++o) { float w = row[o]; aq += w * qv[o]; ak += w * kv[o]; }
    wq[r * CH + i] = aq;
    wk[r * CH + i] = ak;
}

__device__ __forceinline__ void dev_wpack(const float* __restrict__ W,
                                          unsigned short* __restrict__ Wpk, int t) {
    int lane = t & 63, ks = (t >> 6) & 3, ct = (t >> 8) & 7, r = t >> 11;
    int l15 = lane & 15, g = lane >> 4;
    const float* src = W + ((size_t)r * CH + ks * 32 + g * 8) * CH + ct * 16 + l15;
    unsigned pk[4];
    #pragma unroll
    for (int p = 0; p < 4; ++p) {
        unsigned lo = f2bf(src[(2 * p) * CH]);
        unsigned hi = f2bf(src[(2 * p + 1) * CH]);
        pk[p] = lo | (hi << 16);
    }
    *(uint4*)(Wpk + (size_t)t * 8) = make_uint4(pk[0], pk[1], pk[2], pk[3]);
}

__device__ __forceinline__ void dev_qkpack(const float* __restrict__ wq,
                                           const float* __restrict__ wk,
                                           unsigned short* __restrict__ qkf, int tid) {
    int lane = tid & 63, ks = tid >> 6;
    int j = lane & 15, g = lane >> 4;
    const float* col = (j < 8) ? (wq + j * CH) : (wk + (j - 8) * CH);
    int k0 = ks * 32 + g * 8;
    unsigned pk[4];
    #pragma unroll
    for (int p = 0; p < 4; ++p) {
        unsigned lo = f2bf(col[k0 + 2 * p]);
        unsigned hi = f2bf(col[k0 + 2 * p + 1]);
        pk[p] = lo | (hi << 16);
    }
    *(uint4*)(qkf + (size_t)tid * 8) = make_uint4(pk[0], pk[1], pk[2], pk[3]);
}

// ================= fused small kernels =================

__global__ void k_cast_hist(const float* __restrict__ X, unsigned short* __restrict__ Xb,
                            long total, const int* __restrict__ dst,
                            int* __restrict__ count, int ne, int nb_cast) {
    int b = blockIdx.x, tid = threadIdx.x;
    if (b < nb_cast) {
        dev_cast(X, Xb, total, b, tid);
    } else {
        int e = (b - nb_cast) * 256 + tid;
        if (e < ne) atomicAdd(count + dst[e], 1);
    }
}

__global__ __launch_bounds__(256) void k_scan1_wqk(const int* __restrict__ count,
                                                   int* __restrict__ rowptr,
                                                   int* __restrict__ bsum, int n, int nbscan,
                                                   const float* __restrict__ W,
                                                   const float* __restrict__ qv,
                                                   const float* __restrict__ kv,
                                                   float* __restrict__ wq,
                                                   float* __restrict__ wk) {
    int b = blockIdx.x, tid = threadIdx.x;
    if (b >= nbscan) { dev_wqk(W, qv, kv, wq, wk, b - nbscan, tid); return; }
    __shared__ int wsum[4];
    int lane = tid & 63, w = tid >> 6;
    int i0 = b * 1024 + tid * 4;
    int v0 = 0, v1 = 0, v2 = 0, v3 = 0;
    if (i0 + 3 < n) {
        int4 v = *(const int4*)(count + i0);
        v0 = v.x; v1 = v.y; v2 = v.z; v3 = v.w;
    } else {
        if (i0 < n) v0 = count[i0];
        if (i0 + 1 < n) v1 = count[i0 + 1];
        if (i0 + 2 < n) v2 = count[i0 + 2];
        if (i0 + 3 < n) v3 = count[i0 + 3];
    }
    int t1 = v0 + v1, t2 = t1 + v2, t3 = t2 + v3;
    int s = t3;
    #pragma unroll
    for (int off = 1; off < 64; off <<= 1) {
        int t = __shfl_up(s, off);
        if (lane >= off) s += t;
    }
    if (lane == 63) wsum[w] = s;
    __syncthreads();
    int wpre = 0;
    #pragma unroll
    for (int i = 0; i < 4; ++i) wpre += (i < w) ? wsum[i] : 0;
    int excl = wpre + s - t3;
    if (i0 < n) rowptr[i0] = excl;
    if (i0 + 1 < n) rowptr[i0 + 1] = excl + v0;
    if (i0 + 2 < n) rowptr[i0 + 2] = excl + t1;
    if (i0 + 3 < n) rowptr[i0 + 3] = excl + t2;
    if (tid == 0) bsum[b] = wsum[0] + wsum[1] + wsum[2] + wsum[3];
}

__global__ __launch_bounds__(256) void k_scan2_wprep(int* __restrict__ bsum,
                                                     int* __restrict__ total, int nb,
                                                     const float* __restrict__ W,
                                                     unsigned short* __restrict__ Wpk,
                                                     const float* __restrict__ wq,
                                                     const float* __restrict__ wk,
                                                     unsigned short* __restrict__ qkf) {
    int b = blockIdx.x, tid = threadIdx.x;
    if (b == 0) {
        if (tid >= 64) return;
        int lane = tid;
        int carry = 0;
        for (int base = 0; base < nb; base += 64) {
            int i = base + lane;
            int v = (i < nb) ? bsum[i] : 0;
            int s = v;
            #pragma unroll
            for (int off = 1; off < 64; off <<= 1) {
                int t = __shfl_up(s, off);
                if (lane >= off) s += t;
            }
            if (i < nb) bsum[i] = carry + s - v;
            carry += __shfl(s, 63);
        }
        if (lane == 0) *total = carry;
    } else if (b <= 64) {
        dev_wpack(W, Wpk, (b - 1) * 256 + tid);
    } else {
        dev_qkpack(wq, wk, qkf, tid);
    }
}

__global__ __launch_bounds__(256) void k_scan3(int* __restrict__ rowptr,
                                               int* __restrict__ rowptr_work,
                                               const int* __restrict__ bsum,
                                               const int* __restrict__ total, int n) {
    int b = blockIdx.x;
    int i0 = b * 1024 + threadIdx.x * 4;
    int add = bsum[b];
    #pragma unroll
    for (int j = 0; j < 4; ++j) {
        int i = i0 + j;
        if (i < n) {
            int v = rowptr[i] + add;
            rowptr[i] = v;
            rowptr_work[i] = v;
        }
    }
    if (b == 0 && threadIdx.x == 0) rowptr[n] = *total;
}

// ================= standalone gemm: relation-resident W, fp8 XW output =================

__global__ __launch_bounds__(256) void k_gemm3(const unsigned short* __restrict__ Xb,
                                               const unsigned short* __restrict__ Wpk,
                                               unsigned char* __restrict__ XW,
                                               int n, int nwaves) {
    const int wv = threadIdx.x >> 6, lane = threadIdx.x & 63;
    const int l15 = lane & 15, g = lane >> 4;
    const int w = blockIdx.x * 4 + wv;
    const int r = w & 7;
    const int slot = w >> 3;
    const int nslots = nwaves >> 3;
    const int ntiles = (n + 15) >> 4;

    short8 wf[8][4];
    const unsigned short* wr = Wpk + ((size_t)r * 32 * 64 + lane) * 8;
    #pragma unroll
    for (int ct = 0; ct < 8; ++ct)
        #pragma unroll
        for (int ks = 0; ks < 4; ++ks)
            wf[ct][ks] = *(const short8*)(wr + (size_t)(ct * 4 + ks) * 64 * 8);

    for (int t = slot; t < ntiles; t += nslots) {
        int row = t * 16 + l15;
        bool ok = row < n;
        int rowc = ok ? row : n - 1;
        const unsigned short* xrow = Xb + (size_t)rowc * CH + g * 8;
        short8 xf[4];
        #pragma unroll
        for (int ks = 0; ks < 4; ++ks) xf[ks] = *(const short8*)(xrow + ks * 32);
        unsigned char* orow = XW + ((size_t)r * n + row) * CH;
        #pragma unroll
        for (int ct = 0; ct < 8; ++ct) {
            f32x4 a = {0.f, 0.f, 0.f, 0.f};
            #pragma unroll
            for (int ks = 0; ks < 4; ++ks)
                a = __builtin_amdgcn_mfma_f32_16x16x32_bf16(wf[ct][ks], xf[ks], a, 0, 0, 0);
            int wd = 0;
            wd = __builtin_amdgcn_cvt_pk_fp8_f32(a[0], a[1], wd, false);
            wd = __builtin_amdgcn_cvt_pk_fp8_f32(a[2], a[3], wd, true);
            if (ok) *(unsigned*)(orow + ct * 16 + g * 4) = (unsigned)wd;
        }
    }
}

// ================= standalone sqsk (R8-verified) =================

__global__ __launch_bounds__(256) void k_sqsk2(const unsigned short* __restrict__ Xb,
                                               const unsigned short* __restrict__ qkf,
                                               float* __restrict__ sq,
                                               float* __restrict__ sk, int n) {
    const int wv = threadIdx.x >> 6, lane = threadIdx.x & 63;
    const int l15 = lane & 15, g = lane >> 4;
    const int t = blockIdx.x * 4 + wv;
    const int ntiles = (n + 15) >> 4;
    if (t >= ntiles) return;

    short8 qf[4];
    #pragma unroll
    for (int ks = 0; ks < 4; ++ks)
        qf[ks] = *(const short8*)(qkf + (size_t)(ks * 64 + lane) * 8);

    int row = t * 16 + l15;
    bool ok = row < n;
    int rowc = ok ? row : n - 1;
    const unsigned short* xrow = Xb + (size_t)rowc * CH + g * 8;
    short8 xf[4];
    #pragma unroll
    for (int ks = 0; ks < 4; ++ks) xf[ks] = *(const short8*)(xrow + ks * 32);

    f32x4 dq = {0.f, 0.f, 0.f, 0.f};
    #pragma unroll
    for (int ks = 0; ks < 4; ++ks)
        dq = __builtin_amdgcn_mfma_f32_16x16x32_bf16(qf[ks], xf[ks], dq, 0, 0, 0);

    if (ok) {
        float* base = (g < 2) ? sq : sk;
        int j0 = (g & 1) * 4;
        #pragma unroll
        for (int reg = 0; reg < 4; ++reg)
            base[(size_t)(j0 + reg) * n + row] = dq[reg];
    }
}

// ================= fat kernel (L1 only): gemm || sqsk2 || scatter =================

__global__ __launch_bounds__(256, 1) void k_fat(
    const unsigned short* __restrict__ Xb, const unsigned short* __restrict__ Wpk,
    const unsigned short* __restrict__ qkf, unsigned char* __restrict__ XW,
    float* __restrict__ sq, float* __restrict__ sk, int n, int nwaves,
    int nb_gemm, int nb_sqsk,
    const int* __restrict__ esrc, const int* __restrict__ edst,
    const int* __restrict__ etp, int* __restrict__ rowptr_work,
    int* __restrict__ pe, int ne) {
    const int b = blockIdx.x, tid = threadIdx.x;
    const int wv = tid >> 6, lane = tid & 63;
    const int l15 = lane & 15, g = lane >> 4;
    const int ntiles = (n + 15) >> 4;

    if (b < nb_gemm) {
        const int w = b * 4 + wv;
        const int r = w & 7;
        const int slot = w >> 3;
        const int nslots = nwaves >> 3;

        short8 wf[8][4];
        const unsigned short* wr = Wpk + ((size_t)r * 32 * 64 + lane) * 8;
        #pragma unroll
        for (int ct = 0; ct < 8; ++ct)
            #pragma unroll
            for (int ks = 0; ks < 4; ++ks) {
                wf[ct][ks] = *(const short8*)(wr + (size_t)(ct * 4 + ks) * 64 * 8);
                asm volatile("" : "+v"(wf[ct][ks]));
            }

        for (int t = slot; t < ntiles; t += nslots) {
            int row = t * 16 + l15;
            bool ok = row < n;
            int rowc = ok ? row : n - 1;
            const unsigned short* xrow = Xb + (size_t)rowc * CH + g * 8;
            short8 xf[4];
            #pragma unroll
            for (int ks = 0; ks < 4; ++ks) xf[ks] = *(const short8*)(xrow + ks * 32);
            unsigned char* orow = XW + ((size_t)r * n + row) * CH;
            #pragma unroll
            for (int ct = 0; ct < 8; ++ct) {
                f32x4 a = {0.f, 0.f, 0.f, 0.f};
                #pragma unroll
                for (int ks = 0; ks < 4; ++ks)
                    a = __builtin_amdgcn_mfma_f32_16x16x32_bf16(wf[ct][ks], xf[ks], a, 0, 0, 0);
                int wd = 0;
                wd = __builtin_amdgcn_cvt_pk_fp8_f32(a[0], a[1], wd, false);
                wd = __builtin_amdgcn_cvt_pk_fp8_f32(a[2], a[3], wd, true);
                if (ok) *(unsigned*)(orow + ct * 16 + g * 4) = (unsigned)wd;
            }
        }
    } else if (b < nb_gemm + nb_sqsk) {
        const int t = (b - nb_gemm) * 4 + wv;
        if (t >= ntiles) return;
        short8 qf[4];
        #pragma unroll
        for (int ks = 0; ks < 4; ++ks)
            qf[ks] = *(const short8*)(qkf + (size_t)(ks * 64 + lane) * 8);
        int row = t * 16 + l15;
        bool ok = row < n;
        int rowc = ok ? row : n - 1;
        const unsigned short* xrow = Xb + (size_t)rowc * CH + g * 8;
        short8 xf[4];
        #pragma unroll
        for (int ks = 0; ks < 4; ++ks) xf[ks] = *(const short8*)(xrow + ks * 32);
        f32x4 dq = {0.f, 0.f, 0.f, 0.f};
        #pragma unroll
        for (int ks = 0; ks < 4; ++ks)
            dq = __builtin_amdgcn_mfma_f32_16x16x32_bf16(qf[ks], xf[ks], dq, 0, 0, 0);
        if (ok) {
            float* base = (g < 2) ? sq : sk;
            int j0 = (g & 1) * 4;
            #pragma unroll
            for (int reg = 0; reg < 4; ++reg)
                base[(size_t)(j0 + reg) * n + row] = dq[reg];
        }
    } else {
        int e = (b - nb_gemm - nb_sqsk) * 256 + tid;
        if (e >= ne) return;
        int pos = atomicAdd(rowptr_work + edst[e], 1);
        pe[pos] = (esrc[e] & 0xffff) | (etp[e] << 16);
    }
}

// ================= attn: single pass, fp8 XW gather (+ optional next-layer wqk) =================

__global__ __launch_bounds__(256) void k_attn_wqk(
    const int* __restrict__ rowptr, const int* __restrict__ pe,
    const float* __restrict__ sq, const float* __restrict__ sk,
    const unsigned char* __restrict__ XW, const float* __restrict__ bias,
    unsigned short* __restrict__ outb, int n_nodes,
    const float* __restrict__ Wn, const float* __restrict__ qn,
    const float* __restrict__ kn, float* __restrict__ wqn,
    float* __restrict__ wkn, int nb_wqk) {
    int b = blockIdx.x;
    if (b < nb_wqk) { dev_wqk(Wn, qn, kn, wqn, wkn, b, threadIdx.x); return; }
    int wid = ((b - nb_wqk) * 256 + threadIdx.x) >> 6;
    int lane = threadIdx.x & 63;
    if (wid >= n_nodes) return;
    const int l16 = lane & 15, g16 = lane >> 4;
    int r0 = rowptr[wid], r1 = rowptr[wid + 1];
    float acc[8] = {};
    float denom = 0.f;

    if (r1 > r0) {
        float sqv = (lane < N_REL) ? sq[lane * n_nodes + wid] : 0.f;

        for (int c0 = r0; c0 < r1; c0 += 64) {
            int j = c0 + lane;
            float ev = 0.f;
            int p = 0;
            if (j < r1) {
                p = pe[j];
                int s = p & 0xffff, t = p >> 16;
                float av = __shfl(sqv, t) + sk[t * n_nodes + s];
                av = av >= 0.f ? av : NEG_SLOPE * av;
                ev = __expf(fminf(av, 80.f));
            }
            float evs = ev;
            #pragma unroll
            for (int off = 32; off; off >>= 1) evs += __shfl_xor(evs, off);
            denom += evs;

            int C = r1 - c0;
            if (C > 64) C = 64;
            for (int jj = 0; jj < C; jj += 4) {
                int lsel = jj + g16;
                float evj = __shfl(ev, lsel);
                int pj = __shfl(p, lsel);
                int s = pj & 0xffff, t = pj >> 16;
                const unsigned char* row = XW + ((size_t)(t * n_nodes + s)) * CH + l16 * 8;
                uint2 v = *(const uint2*)row;
                f32x2 p0 = __builtin_amdgcn_cvt_pk_f32_fp8(v.x, false);
                f32x2 p1 = __builtin_amdgcn_cvt_pk_f32_fp8(v.x, true);
                f32x2 p2 = __builtin_amdgcn_cvt_pk_f32_fp8(v.y, false);
                f32x2 p3 = __builtin_amdgcn_cvt_pk_f32_fp8(v.y, true);
                acc[0] += evj * p0[0];
                acc[1] += evj * p0[1];
                acc[2] += evj * p1[0];
                acc[3] += evj * p1[1];
                acc[4] += evj * p2[0];
                acc[5] += evj * p2[1];
                acc[6] += evj * p3[0];
                acc[7] += evj * p3[1];
            }
        }
    }

    #pragma unroll
    for (int i = 0; i < 8; ++i) {
        acc[i] += __shfl_xor(acc[i], 16);
        acc[i] += __shfl_xor(acc[i], 32);
    }

    if (lane < 16) {
        float inv = denom > 0.f ? 1.f / denom : 0.f;
        unsigned pk[4];
        #pragma unroll
        for (int i = 0; i < 4; ++i) {
            float b0 = bias[l16 * 8 + 2 * i];
            float b1 = bias[l16 * 8 + 2 * i + 1];
            float o0 = acc[2 * i] * inv + b0;
            float o1 = acc[2 * i + 1] * inv + b1;
            o0 = o0 > 0.f ? o0 : 0.f;
            o1 = o1 > 0.f ? o1 : 0.f;
            pk[i] = (unsigned)f2bf(o0) | ((unsigned)f2bf(o1) << 16);
        }
        *(uint4*)(outb + (size_t)wid * CH + l16 * 8) = make_uint4(pk[0], pk[1], pk[2], pk[3]);
    }
}

// ================= tail =================

__global__ __launch_bounds__(256) void k_colsum(const unsigned short* __restrict__ h,
                                                float* __restrict__ sum, int n_nodes) {
    __shared__ float cs[CH];
    int tid = threadIdx.x;
    int c2 = (tid & 63) * 2;
    int rw = tid >> 6;
    if (tid < CH) cs[tid] = 0.f;
    __syncthreads();
    float a0 = 0.f, a1 = 0.f;
    for (int row = blockIdx.x * 4 + rw; row < n_nodes; row += gridDim.x * 4) {
        unsigned v = *(const unsigned*)(h + (size_t)row * CH + c2);
        a0 += __uint_as_float(v << 16);
        a1 += __uint_as_float(v & 0xffff0000u);
    }
    atomicAdd(&cs[c2], a0);
    atomicAdd(&cs[c2 + 1], a1);
    __syncthreads();
    if (tid < CH) atomicAdd(sum + tid, cs[tid]);
}

// ================= layer-2 W prep (wpack || qkpack) =================

__global__ __launch_bounds__(256) void k_wprep2(const float* __restrict__ W,
                                                unsigned short* __restrict__ Wpk,
                                                const float* __restrict__ wq,
                                                const float* __restrict__ wk,
                                                unsigned short* __restrict__ qkf) {
    int b = blockIdx.x, tid = threadIdx.x;
    if (b < 64) dev_wpack(W, Wpk, b * 256 + tid);
    else dev_qkpack(wq, wk, qkf, tid);
}

__global__ void k_head(const float* __restrict__ sum, const float* __restrict__ lw,
                       const float* __restrict__ lb, float* __restrict__ outp, int n_nodes) {
    __shared__ float mean[CH];
    int t = threadIdx.x;  // 128
    mean[t] = sum[t] / (float)n_nodes;
    __syncthreads();
    if (t < OUT_CH) {
        float g = lb[t];
        for (int i = 0; i < CH; ++i) g += mean[i] * lw[i * OUT_CH + t];
        float m = g;
        #pragma unroll
        for (int off = 8; off; off >>= 1) m = fmaxf(m, __shfl_xor(m, off, 16));
        float ex = expf(g - m);
        float se = ex;
        #pragma unroll
        for (int off = 8; off; off >>= 1) se += __shfl_xor(se, off, 16);
        outp[t] = g - m - logf(se);
    }
}

extern "C" void kernel_launch(void* const* d_in, const int* in_sizes, int n_in,
                              void* d_out, int out_size, void* d_ws, size_t ws_size,
                              hipStream_t stream) {
    const float* x  = (const float*)d_in[0];
    const float* W1 = (const float*)d_in[1];
    const float* q1 = (const float*)d_in[2];
    const float* k1 = (const float*)d_in[3];
    const float* b1 = (const float*)d_in[4];
    const float* W2 = (const float*)d_in[5];
    const float* q2 = (const float*)d_in[6];
    const float* k2 = (const float*)d_in[7];
    const float* b2 = (const float*)d_in[8];
    const float* lw = (const float*)d_in[9];
    const float* lb = (const float*)d_in[10];
    const int* ei   = (const int*)d_in[11];
    const int* etp  = (const int*)d_in[12];

    const int n  = in_sizes[0] / CH;
    const int ne = in_sizes[12];
    const int* esrc = ei;
    const int* edst = ei + ne;

    char* ws = (char*)d_ws;
    size_t off = 0;
    auto carve = [&](size_t bytes) -> char* {
        char* p = ws + off;
        off = (off + bytes + 255) & ~(size_t)255;
        return p;
    };
    unsigned char* xw   = (unsigned char*)carve((size_t)N_REL * n * CH);
    unsigned short* xb  = (unsigned short*)carve((size_t)n * CH * 2);
    unsigned short* h1b = (unsigned short*)carve((size_t)n * CH * 2);
    unsigned short* h2b = (unsigned short*)carve((size_t)n * CH * 2);
    unsigned short* wpk = (unsigned short*)carve((size_t)N_REL * 32 * 64 * 8 * 2);
    unsigned short* qkf = (unsigned short*)carve((size_t)256 * 8 * 2);
    float* sq     = (float*)carve((size_t)N_REL * n * 4);
    float* sk     = (float*)carve((size_t)N_REL * n * 4);
    float* wq     = (float*)carve(N_REL * CH * 4);
    float* wk     = (float*)carve(N_REL * CH * 4);
    int* count    = (int*)carve((size_t)n * 4);
    int* rowptr   = (int*)carve((size_t)(n + 1) * 4);
    int* rowptr_w = (int*)carve((size_t)n * 4);
    int* pe       = (int*)carve((size_t)ne * 4);
    int* bsum     = (int*)carve((size_t)256 * 4);
    int* total    = (int*)carve(4);
    float* sum128 = (float*)carve(CH * 4);

    hipMemsetAsync(count, 0, (size_t)n * 4, stream);
    hipMemsetAsync(sum128, 0, CH * 4, stream);

    const int nbscan = (n + 1023) / 1024;
    const int nb_cast = (int)(((long)n * CH / 8 + 255) / 256);
    const int nb_hist = (ne + 255) / 256;
    const int NW = 4096;                              // 2x TLP for the latency-bound gemm
    const int nb_gemm = NW / 4;                       // 1024
    const int ntiles = (n + 15) >> 4;
    const int nb_sqsk = (ntiles + 3) / 4;             // 782
    const int nb_scat = (ne + 255) / 256;             // 2344
    const int nb_attn = (n + 3) / 4;                  // 12500

    // cast || hist
    k_cast_hist<<<nb_cast + nb_hist, 256, 0, stream>>>(x, xb, (long)n * CH, edst, count, ne, nb_cast);
    // scan1 || wqk(L1)
    k_scan1_wqk<<<nbscan + 4, 256, 0, stream>>>(count, rowptr, bsum, n, nbscan, W1, q1, k1, wq, wk);
    // scan2 || wpack(L1) || qkpack(L1)
    k_scan2_wprep<<<66, 256, 0, stream>>>(bsum, total, nbscan, W1, wpk, wq, wk, qkf);
    k_scan3<<<nbscan, 256, 0, stream>>>(rowptr, rowptr_w, bsum, total, n);
    // layer 1: gemm || sqsk || scatter (fat — scatter hiding pays here)
    k_fat<<<nb_gemm + nb_sqsk + nb_scat, 256, 0, stream>>>(xb, wpk, qkf, xw, sq, sk, n, NW,
                                                           nb_gemm, nb_sqsk,
                                                           esrc, edst, etp, rowptr_w, pe, ne);
    // attn(L1) || wqk(L2)
    k_attn_wqk<<<4 + nb_attn, 256, 0, stream>>>(rowptr, pe, sq, sk, xw, b1, h1b, n,
                                                W2, q2, k2, wq, wk, 4);
    // wpack(L2) || qkpack(L2)
    k_wprep2<<<65, 256, 0, stream>>>(W2, wpk, wq, wk, qkf);
    // layer 2: standalone gemm + sqsk (own regalloc -> W stays resident)
    k_gemm3<<<nb_gemm, 256, 0, stream>>>(h1b, wpk, xw, n, NW);
    k_sqsk2<<<(ntiles + 3) / 4, 256, 0, stream>>>(h1b, qkf, sq, sk, n);
    // attn(L2)
    k_attn_wqk<<<nb_attn, 256, 0, stream>>>(rowptr, pe, sq, sk, xw, b2, h2b, n,
                                            (const float*)nullptr, (const float*)nullptr,
                                            (const float*)nullptr, (float*)nullptr,
                                            (float*)nullptr, 0);

    k_colsum<<<256, 256, 0, stream>>>(h2b, sum128, n);
    k_head<<<1, CH, 0, stream>>>(sum128, lw, lb, (float*)d_out, n);
}

// Round 18
// 227.926 us; speedup vs baseline: 1.1030x; 1.1030x over previous
//
#include <hip/hip_runtime.h>

#define CH 128
#define N_REL 8
#define OUT_CH 16
#define NEG_SLOPE 0.2f

typedef short short8 __attribute__((ext_vector_type(8)));
typedef float f32x4 __attribute__((ext_vector_type(4)));
typedef float f32x2 __attribute__((ext_vector_type(2)));

// ---------- helpers ----------
__device__ __forceinline__ unsigned short f2bf(float f) {  // RTN-even f32->bf16
    unsigned u = __float_as_uint(f);
    return (unsigned short)((u + 0x7fffu + ((u >> 16) & 1u)) >> 16);
}

// ================= device bodies =================

__device__ __forceinline__ void dev_cast(const float* __restrict__ X,
                                         unsigned short* __restrict__ Xb,
                                         long total, int b, int tid) {
    long i = ((long)b * 256 + tid) * 8;
    if (i >= total) return;
    float4 v0 = *(const float4*)(X + i);
    float4 v1 = *(const float4*)(X + i + 4);
    ushort4 a, c;
    a.x = f2bf(v0.x); a.y = f2bf(v0.y); a.z = f2bf(v0.z); a.w = f2bf(v0.w);
    c.x = f2bf(v1.x); c.y = f2bf(v1.y); c.z = f2bf(v1.z); c.w = f2bf(v1.w);
    *(ushort4*)(Xb + i) = a;
    *(ushort4*)(Xb + i + 4) = c;
}

__device__ __forceinline__ void dev_wqk(const float* __restrict__ W,
                                        const float* __restrict__ qv,
                                        const float* __restrict__ kv,
                                        float* __restrict__ wq, float* __restrict__ wk,
                                        int rb, int tid) {
    int r = rb * 2 + (tid >> 7);
    int i = tid & 127;
    const float* row = W + ((size_t)r * CH + i) * CH;
    float aq = 0.f, ak = 0.f;
    for (int o = 0; o < CH; ++o) { float w = row[o]; aq += w * qv[o]; ak += w * kv[o]; }
    wq[r * CH + i] = aq;
    wk[r * CH + i] = ak;
}

__device__ __forceinline__ void dev_wpack(const float* __restrict__ W,
                                          unsigned short* __restrict__ Wpk, int t) {
    int lane = t & 63, ks = (t >> 6) & 3, ct = (t >> 8) & 7, r = t >> 11;
    int l15 = lane & 15, g = lane >> 4;
    const float* src = W + ((size_t)r * CH + ks * 32 + g * 8) * CH + ct * 16 + l15;
    unsigned pk[4];
    #pragma unroll
    for (int p = 0; p < 4; ++p) {
        unsigned lo = f2bf(src[(2 * p) * CH]);
        unsigned hi = f2bf(src[(2 * p + 1) * CH]);
        pk[p] = lo | (hi << 16);
    }
    *(uint4*)(Wpk + (size_t)t * 8) = make_uint4(pk[0], pk[1], pk[2], pk[3]);
}

__device__ __forceinline__ void dev_qkpack(const float* __restrict__ wq,
                                           const float* __restrict__ wk,
                                           unsigned short* __restrict__ qkf, int tid) {
    int lane = tid & 63, ks = tid >> 6;
    int j = lane & 15, g = lane >> 4;
    const float* col = (j < 8) ? (wq + j * CH) : (wk + (j - 8) * CH);
    int k0 = ks * 32 + g * 8;
    unsigned pk[4];
    #pragma unroll
    for (int p = 0; p < 4; ++p) {
        unsigned lo = f2bf(col[k0 + 2 * p]);
        unsigned hi = f2bf(col[k0 + 2 * p + 1]);
        pk[p] = lo | (hi << 16);
    }
    *(uint4*)(qkf + (size_t)tid * 8) = make_uint4(pk[0], pk[1], pk[2], pk[3]);
}

// ================= fused small kernels =================

__global__ void k_cast_hist(const float* __restrict__ X, unsigned short* __restrict__ Xb,
                            long total, const int* __restrict__ dst,
                            int* __restrict__ count, int ne, int nb_cast) {
    int b = blockIdx.x, tid = threadIdx.x;
    if (b < nb_cast) {
        dev_cast(X, Xb, total, b, tid);
    } else {
        int e = (b - nb_cast) * 256 + tid;
        if (e < ne) atomicAdd(count + dst[e], 1);
    }
}

__global__ __launch_bounds__(256) void k_scan1_wqk(const int* __restrict__ count,
                                                   int* __restrict__ rowptr,
                                                   int* __restrict__ bsum, int n, int nbscan,
                                                   const float* __restrict__ W,
                                                   const float* __restrict__ qv,
                                                   const float* __restrict__ kv,
                                                   float* __restrict__ wq,
                                                   float* __restrict__ wk) {
    int b = blockIdx.x, tid = threadIdx.x;
    if (b >= nbscan) { dev_wqk(W, qv, kv, wq, wk, b - nbscan, tid); return; }
    __shared__ int wsum[4];
    int lane = tid & 63, w = tid >> 6;
    int i0 = b * 1024 + tid * 4;
    int v0 = 0, v1 = 0, v2 = 0, v3 = 0;
    if (i0 + 3 < n) {
        int4 v = *(const int4*)(count + i0);
        v0 = v.x; v1 = v.y; v2 = v.z; v3 = v.w;
    } else {
        if (i0 < n) v0 = count[i0];
        if (i0 + 1 < n) v1 = count[i0 + 1];
        if (i0 + 2 < n) v2 = count[i0 + 2];
        if (i0 + 3 < n) v3 = count[i0 + 3];
    }
    int t1 = v0 + v1, t2 = t1 + v2, t3 = t2 + v3;
    int s = t3;
    #pragma unroll
    for (int off = 1; off < 64; off <<= 1) {
        int t = __shfl_up(s, off);
        if (lane >= off) s += t;
    }
    if (lane == 63) wsum[w] = s;
    __syncthreads();
    int wpre = 0;
    #pragma unroll
    for (int i = 0; i < 4; ++i) wpre += (i < w) ? wsum[i] : 0;
    int excl = wpre + s - t3;
    if (i0 < n) rowptr[i0] = excl;
    if (i0 + 1 < n) rowptr[i0 + 1] = excl + v0;
    if (i0 + 2 < n) rowptr[i0 + 2] = excl + t1;
    if (i0 + 3 < n) rowptr[i0 + 3] = excl + t2;
    if (tid == 0) bsum[b] = wsum[0] + wsum[1] + wsum[2] + wsum[3];
}

__global__ __launch_bounds__(256) void k_scan2_wprep(int* __restrict__ bsum,
                                                     int* __restrict__ total, int nb,
                                                     const float* __restrict__ W,
                                                     unsigned short* __restrict__ Wpk,
                                                     const float* __restrict__ wq,
                                                     const float* __restrict__ wk,
                                                     unsigned short* __restrict__ qkf) {
    int b = blockIdx.x, tid = threadIdx.x;
    if (b == 0) {
        if (tid >= 64) return;
        int lane = tid;
        int carry = 0;
        for (int base = 0; base < nb; base += 64) {
            int i = base + lane;
            int v = (i < nb) ? bsum[i] : 0;
            int s = v;
            #pragma unroll
            for (int off = 1; off < 64; off <<= 1) {
                int t = __shfl_up(s, off);
                if (lane >= off) s += t;
            }
            if (i < nb) bsum[i] = carry + s - v;
            carry += __shfl(s, 63);
        }
        if (lane == 0) *total = carry;
    } else if (b <= 64) {
        dev_wpack(W, Wpk, (b - 1) * 256 + tid);
    } else {
        dev_qkpack(wq, wk, qkf, tid);
    }
}

__global__ __launch_bounds__(256) void k_scan3(int* __restrict__ rowptr,
                                               int* __restrict__ rowptr_work,
                                               const int* __restrict__ bsum,
                                               const int* __restrict__ total, int n) {
    int b = blockIdx.x;
    int i0 = b * 1024 + threadIdx.x * 4;
    int add = bsum[b];
    #pragma unroll
    for (int j = 0; j < 4; ++j) {
        int i = i0 + j;
        if (i < n) {
            int v = rowptr[i] + add;
            rowptr[i] = v;
            rowptr_work[i] = v;
        }
    }
    if (b == 0 && threadIdx.x == 0) rowptr[n] = *total;
}

// ================= standalone gemm: relation-resident W, fp8 XW output =================

__global__ __launch_bounds__(256) void k_gemm3(const unsigned short* __restrict__ Xb,
                                               const unsigned short* __restrict__ Wpk,
                                               unsigned char* __restrict__ XW,
                                               int n, int nwaves) {
    const int wv = threadIdx.x >> 6, lane = threadIdx.x & 63;
    const int l15 = lane & 15, g = lane >> 4;
    const int w = blockIdx.x * 4 + wv;
    const int r = w & 7;
    const int slot = w >> 3;
    const int nslots = nwaves >> 3;
    const int ntiles = (n + 15) >> 4;

    short8 wf[8][4];
    const unsigned short* wr = Wpk + ((size_t)r * 32 * 64 + lane) * 8;
    #pragma unroll
    for (int ct = 0; ct < 8; ++ct)
        #pragma unroll
        for (int ks = 0; ks < 4; ++ks)
            wf[ct][ks] = *(const short8*)(wr + (size_t)(ct * 4 + ks) * 64 * 8);

    for (int t = slot; t < ntiles; t += nslots) {
        int row = t * 16 + l15;
        bool ok = row < n;
        int rowc = ok ? row : n - 1;
        const unsigned short* xrow = Xb + (size_t)rowc * CH + g * 8;
        short8 xf[4];
        #pragma unroll
        for (int ks = 0; ks < 4; ++ks) xf[ks] = *(const short8*)(xrow + ks * 32);
        unsigned char* orow = XW + ((size_t)r * n + row) * CH;
        #pragma unroll
        for (int ct = 0; ct < 8; ++ct) {
            f32x4 a = {0.f, 0.f, 0.f, 0.f};
            #pragma unroll
            for (int ks = 0; ks < 4; ++ks)
                a = __builtin_amdgcn_mfma_f32_16x16x32_bf16(wf[ct][ks], xf[ks], a, 0, 0, 0);
            int wd = 0;
            wd = __builtin_amdgcn_cvt_pk_fp8_f32(a[0], a[1], wd, false);
            wd = __builtin_amdgcn_cvt_pk_fp8_f32(a[2], a[3], wd, true);
            if (ok) *(unsigned*)(orow + ct * 16 + g * 4) = (unsigned)wd;
        }
    }
}

// ================= standalone sqsk (R8-verified) =================

__global__ __launch_bounds__(256) void k_sqsk2(const unsigned short* __restrict__ Xb,
                                               const unsigned short* __restrict__ qkf,
                                               float* __restrict__ sq,
                                               float* __restrict__ sk, int n) {
    const int wv = threadIdx.x >> 6, lane = threadIdx.x & 63;
    const int l15 = lane & 15, g = lane >> 4;
    const int t = blockIdx.x * 4 + wv;
    const int ntiles = (n + 15) >> 4;
    if (t >= ntiles) return;

    short8 qf[4];
    #pragma unroll
    for (int ks = 0; ks < 4; ++ks)
        qf[ks] = *(const short8*)(qkf + (size_t)(ks * 64 + lane) * 8);

    int row = t * 16 + l15;
    bool ok = row < n;
    int rowc = ok ? row : n - 1;
    const unsigned short* xrow = Xb + (size_t)rowc * CH + g * 8;
    short8 xf[4];
    #pragma unroll
    for (int ks = 0; ks < 4; ++ks) xf[ks] = *(const short8*)(xrow + ks * 32);

    f32x4 dq = {0.f, 0.f, 0.f, 0.f};
    #pragma unroll
    for (int ks = 0; ks < 4; ++ks)
        dq = __builtin_amdgcn_mfma_f32_16x16x32_bf16(qf[ks], xf[ks], dq, 0, 0, 0);

    if (ok) {
        float* base = (g < 2) ? sq : sk;
        int j0 = (g & 1) * 4;
        #pragma unroll
        for (int reg = 0; reg < 4; ++reg)
            base[(size_t)(j0 + reg) * n + row] = dq[reg];
    }
}

// ================= fat kernel (L1 only): gemm || sqsk2 || scatter =================

__global__ __launch_bounds__(256, 1) void k_fat(
    const unsigned short* __restrict__ Xb, const unsigned short* __restrict__ Wpk,
    const unsigned short* __restrict__ qkf, unsigned char* __restrict__ XW,
    float* __restrict__ sq, float* __restrict__ sk, int n, int nwaves,
    int nb_gemm, int nb_sqsk,
    const int* __restrict__ esrc, const int* __restrict__ edst,
    const int* __restrict__ etp, int* __restrict__ rowptr_work,
    int* __restrict__ pe, int ne) {
    const int b = blockIdx.x, tid = threadIdx.x;
    const int wv = tid >> 6, lane = tid & 63;
    const int l15 = lane & 15, g = lane >> 4;
    const int ntiles = (n + 15) >> 4;

    if (b < nb_gemm) {
        const int w = b * 4 + wv;
        const int r = w & 7;
        const int slot = w >> 3;
        const int nslots = nwaves >> 3;

        short8 wf[8][4];
        const unsigned short* wr = Wpk + ((size_t)r * 32 * 64 + lane) * 8;
        #pragma unroll
        for (int ct = 0; ct < 8; ++ct)
            #pragma unroll
            for (int ks = 0; ks < 4; ++ks) {
                wf[ct][ks] = *(const short8*)(wr + (size_t)(ct * 4 + ks) * 64 * 8);
                asm volatile("" : "+v"(wf[ct][ks]));
            }

        for (int t = slot; t < ntiles; t += nslots) {
            int row = t * 16 + l15;
            bool ok = row < n;
            int rowc = ok ? row : n - 1;
            const unsigned short* xrow = Xb + (size_t)rowc * CH + g * 8;
            short8 xf[4];
            #pragma unroll
            for (int ks = 0; ks < 4; ++ks) xf[ks] = *(const short8*)(xrow + ks * 32);
            unsigned char* orow = XW + ((size_t)r * n + row) * CH;
            #pragma unroll
            for (int ct = 0; ct < 8; ++ct) {
                f32x4 a = {0.f, 0.f, 0.f, 0.f};
                #pragma unroll
                for (int ks = 0; ks < 4; ++ks)
                    a = __builtin_amdgcn_mfma_f32_16x16x32_bf16(wf[ct][ks], xf[ks], a, 0, 0, 0);
                int wd = 0;
                wd = __builtin_amdgcn_cvt_pk_fp8_f32(a[0], a[1], wd, false);
                wd = __builtin_amdgcn_cvt_pk_fp8_f32(a[2], a[3], wd, true);
                if (ok) *(unsigned*)(orow + ct * 16 + g * 4) = (unsigned)wd;
            }
        }
    } else if (b < nb_gemm + nb_sqsk) {
        const int t = (b - nb_gemm) * 4 + wv;
        if (t >= ntiles) return;
        short8 qf[4];
        #pragma unroll
        for (int ks = 0; ks < 4; ++ks)
            qf[ks] = *(const short8*)(qkf + (size_t)(ks * 64 + lane) * 8);
        int row = t * 16 + l15;
        bool ok = row < n;
        int rowc = ok ? row : n - 1;
        const unsigned short* xrow = Xb + (size_t)rowc * CH + g * 8;
        short8 xf[4];
        #pragma unroll
        for (int ks = 0; ks < 4; ++ks) xf[ks] = *(const short8*)(xrow + ks * 32);
        f32x4 dq = {0.f, 0.f, 0.f, 0.f};
        #pragma unroll
        for (int ks = 0; ks < 4; ++ks)
            dq = __builtin_amdgcn_mfma_f32_16x16x32_bf16(qf[ks], xf[ks], dq, 0, 0, 0);
        if (ok) {
            float* base = (g < 2) ? sq : sk;
            int j0 = (g & 1) * 4;
            #pragma unroll
            for (int reg = 0; reg < 4; ++reg)
                base[(size_t)(j0 + reg) * n + row] = dq[reg];
        }
    } else {
        int e = (b - nb_gemm - nb_sqsk) * 256 + tid;
        if (e >= ne) return;
        int pos = atomicAdd(rowptr_work + edst[e], 1);
        pe[pos] = (esrc[e] & 0xffff) | (etp[e] << 16);
    }
}

// ================= attn: single pass, fp8 XW gather (+ optional next-layer wqk) =================

__global__ __launch_bounds__(256) void k_attn_wqk(
    const int* __restrict__ rowptr, const int* __restrict__ pe,
    const float* __restrict__ sq, const float* __restrict__ sk,
    const unsigned char* __restrict__ XW, const float* __restrict__ bias,
    unsigned short* __restrict__ outb, int n_nodes,
    const float* __restrict__ Wn, const float* __restrict__ qn,
    const float* __restrict__ kn, float* __restrict__ wqn,
    float* __restrict__ wkn, int nb_wqk) {
    int b = blockIdx.x;
    if (b < nb_wqk) { dev_wqk(Wn, qn, kn, wqn, wkn, b, threadIdx.x); return; }
    int wid = ((b - nb_wqk) * 256 + threadIdx.x) >> 6;
    int lane = threadIdx.x & 63;
    if (wid >= n_nodes) return;
    const int l16 = lane & 15, g16 = lane >> 4;
    int r0 = rowptr[wid], r1 = rowptr[wid + 1];
    float acc[8] = {};
    float denom = 0.f;

    if (r1 > r0) {
        float sqv = (lane < N_REL) ? sq[lane * n_nodes + wid] : 0.f;

        for (int c0 = r0; c0 < r1; c0 += 64) {
            int j = c0 + lane;
            float ev = 0.f;
            int p = 0;
            if (j < r1) {
                p = pe[j];
                int s = p & 0xffff, t = p >> 16;
                float av = __shfl(sqv, t) + sk[t * n_nodes + s];
                av = av >= 0.f ? av : NEG_SLOPE * av;
                ev = __expf(fminf(av, 80.f));
            }
            float evs = ev;
            #pragma unroll
            for (int off = 32; off; off >>= 1) evs += __shfl_xor(evs, off);
            denom += evs;

            int C = r1 - c0;
            if (C > 64) C = 64;
            for (int jj = 0; jj < C; jj += 4) {
                int lsel = jj + g16;
                float evj = __shfl(ev, lsel);
                int pj = __shfl(p, lsel);
                int s = pj & 0xffff, t = pj >> 16;
                const unsigned char* row = XW + ((size_t)(t * n_nodes + s)) * CH + l16 * 8;
                uint2 v = *(const uint2*)row;
                f32x2 p0 = __builtin_amdgcn_cvt_pk_f32_fp8(v.x, false);
                f32x2 p1 = __builtin_amdgcn_cvt_pk_f32_fp8(v.x, true);
                f32x2 p2 = __builtin_amdgcn_cvt_pk_f32_fp8(v.y, false);
                f32x2 p3 = __builtin_amdgcn_cvt_pk_f32_fp8(v.y, true);
                acc[0] += evj * p0[0];
                acc[1] += evj * p0[1];
                acc[2] += evj * p1[0];
                acc[3] += evj * p1[1];
                acc[4] += evj * p2[0];
                acc[5] += evj * p2[1];
                acc[6] += evj * p3[0];
                acc[7] += evj * p3[1];
            }
        }
    }

    #pragma unroll
    for (int i = 0; i < 8; ++i) {
        acc[i] += __shfl_xor(acc[i], 16);
        acc[i] += __shfl_xor(acc[i], 32);
    }

    if (lane < 16) {
        float inv = denom > 0.f ? 1.f / denom : 0.f;
        unsigned pk[4];
        #pragma unroll
        for (int i = 0; i < 4; ++i) {
            float b0 = bias[l16 * 8 + 2 * i];
            float b1 = bias[l16 * 8 + 2 * i + 1];
            float o0 = acc[2 * i] * inv + b0;
            float o1 = acc[2 * i + 1] * inv + b1;
            o0 = o0 > 0.f ? o0 : 0.f;
            o1 = o1 > 0.f ? o1 : 0.f;
            pk[i] = (unsigned)f2bf(o0) | ((unsigned)f2bf(o1) << 16);
        }
        *(uint4*)(outb + (size_t)wid * CH + l16 * 8) = make_uint4(pk[0], pk[1], pk[2], pk[3]);
    }
}

// ================= tail =================

__global__ __launch_bounds__(256) void k_colsum(const unsigned short* __restrict__ h,
                                                float* __restrict__ sum, int n_nodes) {
    __shared__ float cs[CH];
    int tid = threadIdx.x;
    int c2 = (tid & 63) * 2;
    int rw = tid >> 6;
    if (tid < CH) cs[tid] = 0.f;
    __syncthreads();
    float a0 = 0.f, a1 = 0.f;
    for (int row = blockIdx.x * 4 + rw; row < n_nodes; row += gridDim.x * 4) {
        unsigned v = *(const unsigned*)(h + (size_t)row * CH + c2);
        a0 += __uint_as_float(v << 16);
        a1 += __uint_as_float(v & 0xffff0000u);
    }
    atomicAdd(&cs[c2], a0);
    atomicAdd(&cs[c2 + 1], a1);
    __syncthreads();
    if (tid < CH) atomicAdd(sum + tid, cs[tid]);
}

// ================= layer-2 W prep (wpack || qkpack) =================

__global__ __launch_bounds__(256) void k_wprep2(const float* __restrict__ W,
                                                unsigned short* __restrict__ Wpk,
                                                const float* __restrict__ wq,
                                                const float* __restrict__ wk,
                                                unsigned short* __restrict__ qkf) {
    int b = blockIdx.x, tid = threadIdx.x;
    if (b < 64) dev_wpack(W, Wpk, b * 256 + tid);
    else dev_qkpack(wq, wk, qkf, tid);
}

__global__ void k_head(const float* __restrict__ sum, const float* __restrict__ lw,
                       const float* __restrict__ lb, float* __restrict__ outp, int n_nodes) {
    __shared__ float mean[CH];
    int t = threadIdx.x;  // 128
    mean[t] = sum[t] / (float)n_nodes;
    __syncthreads();
    if (t < OUT_CH) {
        float g = lb[t];
        for (int i = 0; i < CH; ++i) g += mean[i] * lw[i * OUT_CH + t];
        float m = g;
        #pragma unroll
        for (int off = 8; off; off >>= 1) m = fmaxf(m, __shfl_xor(m, off, 16));
        float ex = expf(g - m);
        float se = ex;
        #pragma unroll
        for (int off = 8; off; off >>= 1) se += __shfl_xor(se, off, 16);
        outp[t] = g - m - logf(se);
    }
}

extern "C" void kernel_launch(void* const* d_in, const int* in_sizes, int n_in,
                              void* d_out, int out_size, void* d_ws, size_t ws_size,
                              hipStream_t stream) {
    const float* x  = (const float*)d_in[0];
    const float* W1 = (const float*)d_in[1];
    const float* q1 = (const float*)d_in[2];
    const float* k1 = (const float*)d_in[3];
    const float* b1 = (const float*)d_in[4];
    const float* W2 = (const float*)d_in[5];
    const float* q2 = (const float*)d_in[6];
    const float* k2 = (const float*)d_in[7];
    const float* b2 = (const float*)d_in[8];
    const float* lw = (const float*)d_in[9];
    const float* lb = (const float*)d_in[10];
    const int* ei   = (const int*)d_in[11];
    const int* etp  = (const int*)d_in[12];

    const int n  = in_sizes[0] / CH;
    const int ne = in_sizes[12];
    const int* esrc = ei;
    const int* edst = ei + ne;

    char* ws = (char*)d_ws;
    size_t off = 0;
    auto carve = [&](size_t bytes) -> char* {
        char* p = ws + off;
        off = (off + bytes + 255) & ~(size_t)255;
        return p;
    };
    unsigned char* xw   = (unsigned char*)carve((size_t)N_REL * n * CH);
    unsigned short* xb  = (unsigned short*)carve((size_t)n * CH * 2);
    unsigned short* h1b = (unsigned short*)carve((size_t)n * CH * 2);
    unsigned short* h2b = (unsigned short*)carve((size_t)n * CH * 2);
    unsigned short* wpk = (unsigned short*)carve((size_t)N_REL * 32 * 64 * 8 * 2);
    unsigned short* qkf = (unsigned short*)carve((size_t)256 * 8 * 2);
    float* sq     = (float*)carve((size_t)N_REL * n * 4);
    float* sk     = (float*)carve((size_t)N_REL * n * 4);
    float* wq     = (float*)carve(N_REL * CH * 4);
    float* wk     = (float*)carve(N_REL * CH * 4);
    int* count    = (int*)carve((size_t)n * 4);
    int* rowptr   = (int*)carve((size_t)(n + 1) * 4);
    int* rowptr_w = (int*)carve((size_t)n * 4);
    int* pe       = (int*)carve((size_t)ne * 4);
    int* bsum     = (int*)carve((size_t)256 * 4);
    int* total    = (int*)carve(4);
    float* sum128 = (float*)carve(CH * 4);

    hipMemsetAsync(count, 0, (size_t)n * 4, stream);
    hipMemsetAsync(sum128, 0, CH * 4, stream);

    const int nbscan = (n + 1023) / 1024;
    const int nb_cast = (int)(((long)n * CH / 8 + 255) / 256);
    const int nb_hist = (ne + 255) / 256;
    const int NW = 2048;
    const int nb_gemm = NW / 4;                       // 512
    const int ntiles = (n + 15) >> 4;
    const int nb_sqsk = (ntiles + 3) / 4;             // 782
    const int nb_scat = (ne + 255) / 256;             // 2344
    const int nb_attn = (n + 3) / 4;                  // 12500

    // cast || hist
    k_cast_hist<<<nb_cast + nb_hist, 256, 0, stream>>>(x, xb, (long)n * CH, edst, count, ne, nb_cast);
    // scan1 || wqk(L1)
    k_scan1_wqk<<<nbscan + 4, 256, 0, stream>>>(count, rowptr, bsum, n, nbscan, W1, q1, k1, wq, wk);
    // scan2 || wpack(L1) || qkpack(L1)
    k_scan2_wprep<<<66, 256, 0, stream>>>(bsum, total, nbscan, W1, wpk, wq, wk, qkf);
    k_scan3<<<nbscan, 256, 0, stream>>>(rowptr, rowptr_w, bsum, total, n);
    // layer 1: gemm || sqsk || scatter (fat — scatter hiding pays here)
    k_fat<<<nb_gemm + nb_sqsk + nb_scat, 256, 0, stream>>>(xb, wpk, qkf, xw, sq, sk, n, NW,
                                                           nb_gemm, nb_sqsk,
                                                           esrc, edst, etp, rowptr_w, pe, ne);
    // attn(L1) || wqk(L2)
    k_attn_wqk<<<4 + nb_attn, 256, 0, stream>>>(rowptr, pe, sq, sk, xw, b1, h1b, n,
                                                W2, q2, k2, wq, wk, 4);
    // wpack(L2) || qkpack(L2)
    k_wprep2<<<65, 256, 0, stream>>>(W2, wpk, wq, wk, qkf);
    // layer 2: standalone gemm + sqsk (own regalloc -> W stays resident)
    k_gemm3<<<nb_gemm, 256, 0, stream>>>(h1b, wpk, xw, n, NW);
    k_sqsk2<<<(ntiles + 3) / 4, 256, 0, stream>>>(h1b, qkf, sq, sk, n);
    // attn(L2)
    k_attn_wqk<<<nb_attn, 256, 0, stream>>>(rowptr, pe, sq, sk, xw, b2, h2b, n,
                                            (const float*)nullptr, (const float*)nullptr,
                                            (const float*)nullptr, (float*)nullptr,
                                            (float*)nullptr, 0);

    k_colsum<<<256, 256, 0, stream>>>(h2b, sum128, n);
    k_head<<<1, CH, 0, stream>>>(sum128, lw, lb, (float*)d_out, n);
}

// Round 19
// 227.431 us; speedup vs baseline: 1.1054x; 1.0022x over previous
//
#include <hip/hip_runtime.h>

#define CH 128
#define N_REL 8
#define OUT_CH 16
#define NEG_SLOPE 0.2f

typedef short short8 __attribute__((ext_vector_type(8)));
typedef float f32x4 __attribute__((ext_vector_type(4)));
typedef float f32x2 __attribute__((ext_vector_type(2)));

// ---------- helpers ----------
__device__ __forceinline__ unsigned short f2bf(float f) {  // RTN-even f32->bf16
    unsigned u = __float_as_uint(f);
    return (unsigned short)((u + 0x7fffu + ((u >> 16) & 1u)) >> 16);
}

// ================= device bodies =================

__device__ __forceinline__ void dev_cast(const float* __restrict__ X,
                                         unsigned short* __restrict__ Xb,
                                         long total, int b, int tid) {
    long i = ((long)b * 256 + tid) * 8;
    if (i >= total) return;
    float4 v0 = *(const float4*)(X + i);
    float4 v1 = *(const float4*)(X + i + 4);
    ushort4 a, c;
    a.x = f2bf(v0.x); a.y = f2bf(v0.y); a.z = f2bf(v0.z); a.w = f2bf(v0.w);
    c.x = f2bf(v1.x); c.y = f2bf(v1.y); c.z = f2bf(v1.z); c.w = f2bf(v1.w);
    *(ushort4*)(Xb + i) = a;
    *(ushort4*)(Xb + i + 4) = c;
}

__device__ __forceinline__ void dev_wqk(const float* __restrict__ W,
                                        const float* __restrict__ qv,
                                        const float* __restrict__ kv,
                                        float* __restrict__ wq, float* __restrict__ wk,
                                        int rb, int tid) {
    int r = rb * 2 + (tid >> 7);
    int i = tid & 127;
    const float* row = W + ((size_t)r * CH + i) * CH;
    float aq = 0.f, ak = 0.f;
    for (int o = 0; o < CH; ++o) { float w = row[o]; aq += w * qv[o]; ak += w * kv[o]; }
    wq[r * CH + i] = aq;
    wk[r * CH + i] = ak;
}

__device__ __forceinline__ void dev_wpack(const float* __restrict__ W,
                                          unsigned short* __restrict__ Wpk, int t) {
    int lane = t & 63, ks = (t >> 6) & 3, ct = (t >> 8) & 7, r = t >> 11;
    int l15 = lane & 15, g = lane >> 4;
    const float* src = W + ((size_t)r * CH + ks * 32 + g * 8) * CH + ct * 16 + l15;
    unsigned pk[4];
    #pragma unroll
    for (int p = 0; p < 4; ++p) {
        unsigned lo = f2bf(src[(2 * p) * CH]);
        unsigned hi = f2bf(src[(2 * p + 1) * CH]);
        pk[p] = lo | (hi << 16);
    }
    *(uint4*)(Wpk + (size_t)t * 8) = make_uint4(pk[0], pk[1], pk[2], pk[3]);
}

__device__ __forceinline__ void dev_qkpack(const float* __restrict__ wq,
                                           const float* __restrict__ wk,
                                           unsigned short* __restrict__ qkf, int tid) {
    int lane = tid & 63, ks = tid >> 6;
    int j = lane & 15, g = lane >> 4;
    const float* col = (j < 8) ? (wq + j * CH) : (wk + (j - 8) * CH);
    int k0 = ks * 32 + g * 8;
    unsigned pk[4];
    #pragma unroll
    for (int p = 0; p < 4; ++p) {
        unsigned lo = f2bf(col[k0 + 2 * p]);
        unsigned hi = f2bf(col[k0 + 2 * p + 1]);
        pk[p] = lo | (hi << 16);
    }
    *(uint4*)(qkf + (size_t)tid * 8) = make_uint4(pk[0], pk[1], pk[2], pk[3]);
}

// ================= fused small kernels =================

__global__ void k_cast_hist(const float* __restrict__ X, unsigned short* __restrict__ Xb,
                            long total, const int* __restrict__ dst,
                            int* __restrict__ count, int ne, int nb_cast) {
    int b = blockIdx.x, tid = threadIdx.x;
    if (b < nb_cast) {
        dev_cast(X, Xb, total, b, tid);
    } else {
        int e = (b - nb_cast) * 256 + tid;
        if (e < ne) atomicAdd(count + dst[e], 1);
    }
}

// scan1: per-1024-chunk exclusive scan, CHUNK-LOCAL values into rowptr AND rowptr_work.
// Global offset bsum[chunk] is folded in at consumption (scatter/attn) — no scan3 pass.
__global__ __launch_bounds__(256) void k_scan1_wqk(const int* __restrict__ count,
                                                   int* __restrict__ rowptr,
                                                   int* __restrict__ rowptr_work,
                                                   int* __restrict__ bsum, int n, int nbscan,
                                                   const float* __restrict__ W,
                                                   const float* __restrict__ qv,
                                                   const float* __restrict__ kv,
                                                   float* __restrict__ wq,
                                                   float* __restrict__ wk) {
    int b = blockIdx.x, tid = threadIdx.x;
    if (b >= nbscan) { dev_wqk(W, qv, kv, wq, wk, b - nbscan, tid); return; }
    __shared__ int wsum[4];
    int lane = tid & 63, w = tid >> 6;
    int i0 = b * 1024 + tid * 4;
    int v0 = 0, v1 = 0, v2 = 0, v3 = 0;
    if (i0 + 3 < n) {
        int4 v = *(const int4*)(count + i0);
        v0 = v.x; v1 = v.y; v2 = v.z; v3 = v.w;
    } else {
        if (i0 < n) v0 = count[i0];
        if (i0 + 1 < n) v1 = count[i0 + 1];
        if (i0 + 2 < n) v2 = count[i0 + 2];
        if (i0 + 3 < n) v3 = count[i0 + 3];
    }
    int t1 = v0 + v1, t2 = t1 + v2, t3 = t2 + v3;
    int s = t3;
    #pragma unroll
    for (int off = 1; off < 64; off <<= 1) {
        int t = __shfl_up(s, off);
        if (lane >= off) s += t;
    }
    if (lane == 63) wsum[w] = s;
    __syncthreads();
    int wpre = 0;
    #pragma unroll
    for (int i = 0; i < 4; ++i) wpre += (i < w) ? wsum[i] : 0;
    int excl = wpre + s - t3;
    if (i0 < n)     { rowptr[i0]     = excl;      rowptr_work[i0]     = excl; }
    if (i0 + 1 < n) { rowptr[i0 + 1] = excl + v0; rowptr_work[i0 + 1] = excl + v0; }
    if (i0 + 2 < n) { rowptr[i0 + 2] = excl + t1; rowptr_work[i0 + 2] = excl + t1; }
    if (i0 + 3 < n) { rowptr[i0 + 3] = excl + t2; rowptr_work[i0 + 3] = excl + t2; }
    if (tid == 0) bsum[b] = wsum[0] + wsum[1] + wsum[2] + wsum[3];
}

__global__ __launch_bounds__(256) void k_scan2_wprep(int* __restrict__ bsum,
                                                     int* __restrict__ total, int nb,
                                                     const float* __restrict__ W,
                                                     unsigned short* __restrict__ Wpk,
                                                     const float* __restrict__ wq,
                                                     const float* __restrict__ wk,
                                                     unsigned short* __restrict__ qkf) {
    int b = blockIdx.x, tid = threadIdx.x;
    if (b == 0) {
        if (tid >= 64) return;
        int lane = tid;
        int carry = 0;
        for (int base = 0; base < nb; base += 64) {
            int i = base + lane;
            int v = (i < nb) ? bsum[i] : 0;
            int s = v;
            #pragma unroll
            for (int off = 1; off < 64; off <<= 1) {
                int t = __shfl_up(s, off);
                if (lane >= off) s += t;
            }
            if (i < nb) bsum[i] = carry + s - v;
            carry += __shfl(s, 63);
        }
        if (lane == 0) *total = carry;
    } else if (b <= 64) {
        dev_wpack(W, Wpk, (b - 1) * 256 + tid);
    } else {
        dev_qkpack(wq, wk, qkf, tid);
    }
}

// ================= standalone gemm: relation-resident W, fp8 XW output =================

__global__ __launch_bounds__(256) void k_gemm3(const unsigned short* __restrict__ Xb,
                                               const unsigned short* __restrict__ Wpk,
                                               unsigned char* __restrict__ XW,
                                               int n, int nwaves) {
    const int wv = threadIdx.x >> 6, lane = threadIdx.x & 63;
    const int l15 = lane & 15, g = lane >> 4;
    const int w = blockIdx.x * 4 + wv;
    const int r = w & 7;
    const int slot = w >> 3;
    const int nslots = nwaves >> 3;
    const int ntiles = (n + 15) >> 4;

    short8 wf[8][4];
    const unsigned short* wr = Wpk + ((size_t)r * 32 * 64 + lane) * 8;
    #pragma unroll
    for (int ct = 0; ct < 8; ++ct)
        #pragma unroll
        for (int ks = 0; ks < 4; ++ks)
            wf[ct][ks] = *(const short8*)(wr + (size_t)(ct * 4 + ks) * 64 * 8);

    for (int t = slot; t < ntiles; t += nslots) {
        int row = t * 16 + l15;
        bool ok = row < n;
        int rowc = ok ? row : n - 1;
        const unsigned short* xrow = Xb + (size_t)rowc * CH + g * 8;
        short8 xf[4];
        #pragma unroll
        for (int ks = 0; ks < 4; ++ks) xf[ks] = *(const short8*)(xrow + ks * 32);
        unsigned char* orow = XW + ((size_t)r * n + row) * CH;
        #pragma unroll
        for (int ct = 0; ct < 8; ++ct) {
            f32x4 a = {0.f, 0.f, 0.f, 0.f};
            #pragma unroll
            for (int ks = 0; ks < 4; ++ks)
                a = __builtin_amdgcn_mfma_f32_16x16x32_bf16(wf[ct][ks], xf[ks], a, 0, 0, 0);
            int wd = 0;
            wd = __builtin_amdgcn_cvt_pk_fp8_f32(a[0], a[1], wd, false);
            wd = __builtin_amdgcn_cvt_pk_fp8_f32(a[2], a[3], wd, true);
            if (ok) *(unsigned*)(orow + ct * 16 + g * 4) = (unsigned)wd;
        }
    }
}

// ================= standalone sqsk (R8-verified) =================

__global__ __launch_bounds__(256) void k_sqsk2(const unsigned short* __restrict__ Xb,
                                               const unsigned short* __restrict__ qkf,
                                               float* __restrict__ sq,
                                               float* __restrict__ sk, int n) {
    const int wv = threadIdx.x >> 6, lane = threadIdx.x & 63;
    const int l15 = lane & 15, g = lane >> 4;
    const int t = blockIdx.x * 4 + wv;
    const int ntiles = (n + 15) >> 4;
    if (t >= ntiles) return;

    short8 qf[4];
    #pragma unroll
    for (int ks = 0; ks < 4; ++ks)
        qf[ks] = *(const short8*)(qkf + (size_t)(ks * 64 + lane) * 8);

    int row = t * 16 + l15;
    bool ok = row < n;
    int rowc = ok ? row : n - 1;
    const unsigned short* xrow = Xb + (size_t)rowc * CH + g * 8;
    short8 xf[4];
    #pragma unroll
    for (int ks = 0; ks < 4; ++ks) xf[ks] = *(const short8*)(xrow + ks * 32);

    f32x4 dq = {0.f, 0.f, 0.f, 0.f};
    #pragma unroll
    for (int ks = 0; ks < 4; ++ks)
        dq = __builtin_amdgcn_mfma_f32_16x16x32_bf16(qf[ks], xf[ks], dq, 0, 0, 0);

    if (ok) {
        float* base = (g < 2) ? sq : sk;
        int j0 = (g & 1) * 4;
        #pragma unroll
        for (int reg = 0; reg < 4; ++reg)
            base[(size_t)(j0 + reg) * n + row] = dq[reg];
    }
}

// ================= fat kernel (L1 only): gemm || sqsk2 || scatter =================

__global__ __launch_bounds__(256, 1) void k_fat(
    const unsigned short* __restrict__ Xb, const unsigned short* __restrict__ Wpk,
    const unsigned short* __restrict__ qkf, unsigned char* __restrict__ XW,
    float* __restrict__ sq, float* __restrict__ sk, int n, int nwaves,
    int nb_gemm, int nb_sqsk,
    const int* __restrict__ esrc, const int* __restrict__ edst,
    const int* __restrict__ etp, int* __restrict__ rowptr_work,
    const int* __restrict__ bsum, int* __restrict__ pe, int ne) {
    const int b = blockIdx.x, tid = threadIdx.x;
    const int wv = tid >> 6, lane = tid & 63;
    const int l15 = lane & 15, g = lane >> 4;
    const int ntiles = (n + 15) >> 4;

    if (b < nb_gemm) {
        const int w = b * 4 + wv;
        const int r = w & 7;
        const int slot = w >> 3;
        const int nslots = nwaves >> 3;

        short8 wf[8][4];
        const unsigned short* wr = Wpk + ((size_t)r * 32 * 64 + lane) * 8;
        #pragma unroll
        for (int ct = 0; ct < 8; ++ct)
            #pragma unroll
            for (int ks = 0; ks < 4; ++ks) {
                wf[ct][ks] = *(const short8*)(wr + (size_t)(ct * 4 + ks) * 64 * 8);
                asm volatile("" : "+v"(wf[ct][ks]));
            }

        for (int t = slot; t < ntiles; t += nslots) {
            int row = t * 16 + l15;
            bool ok = row < n;
            int rowc = ok ? row : n - 1;
            const unsigned short* xrow = Xb + (size_t)rowc * CH + g * 8;
            short8 xf[4];
            #pragma unroll
            for (int ks = 0; ks < 4; ++ks) xf[ks] = *(const short8*)(xrow + ks * 32);
            unsigned char* orow = XW + ((size_t)r * n + row) * CH;
            #pragma unroll
            for (int ct = 0; ct < 8; ++ct) {
                f32x4 a = {0.f, 0.f, 0.f, 0.f};
                #pragma unroll
                for (int ks = 0; ks < 4; ++ks)
                    a = __builtin_amdgcn_mfma_f32_16x16x32_bf16(wf[ct][ks], xf[ks], a, 0, 0, 0);
                int wd = 0;
                wd = __builtin_amdgcn_cvt_pk_fp8_f32(a[0], a[1], wd, false);
                wd = __builtin_amdgcn_cvt_pk_fp8_f32(a[2], a[3], wd, true);
                if (ok) *(unsigned*)(orow + ct * 16 + g * 4) = (unsigned)wd;
            }
        }
    } else if (b < nb_gemm + nb_sqsk) {
        const int t = (b - nb_gemm) * 4 + wv;
        if (t >= ntiles) return;
        short8 qf[4];
        #pragma unroll
        for (int ks = 0; ks < 4; ++ks)
            qf[ks] = *(const short8*)(qkf + (size_t)(ks * 64 + lane) * 8);
        int row = t * 16 + l15;
        bool ok = row < n;
        int rowc = ok ? row : n - 1;
        const unsigned short* xrow = Xb + (size_t)rowc * CH + g * 8;
        short8 xf[4];
        #pragma unroll
        for (int ks = 0; ks < 4; ++ks) xf[ks] = *(const short8*)(xrow + ks * 32);
        f32x4 dq = {0.f, 0.f, 0.f, 0.f};
        #pragma unroll
        for (int ks = 0; ks < 4; ++ks)
            dq = __builtin_amdgcn_mfma_f32_16x16x32_bf16(qf[ks], xf[ks], dq, 0, 0, 0);
        if (ok) {
            float* base = (g < 2) ? sq : sk;
            int j0 = (g & 1) * 4;
            #pragma unroll
            for (int reg = 0; reg < 4; ++reg)
                base[(size_t)(j0 + reg) * n + row] = dq[reg];
        }
    } else {
        int e = (b - nb_gemm - nb_sqsk) * 256 + tid;
        if (e >= ne) return;
        int d = edst[e];
        int pos = bsum[d >> 10] + atomicAdd(rowptr_work + d, 1);
        pe[pos] = (esrc[e] & 0xffff) | (etp[e] << 16);
    }
}

// ================= attn: single pass, fp8 XW gather (+ optional next-layer wqk) =================
// rowptr is chunk-local; global offset = bsum[node>>10]; end of last node = ne.

__global__ __launch_bounds__(256) void k_attn_wqk(
    const int* __restrict__ rowptr, const int* __restrict__ bsum,
    const int* __restrict__ pe,
    const float* __restrict__ sq, const float* __restrict__ sk,
    const unsigned char* __restrict__ XW, const float* __restrict__ bias,
    unsigned short* __restrict__ outb, int n_nodes, int ne,
    const float* __restrict__ Wn, const float* __restrict__ qn,
    const float* __restrict__ kn, float* __restrict__ wqn,
    float* __restrict__ wkn, int nb_wqk) {
    int b = blockIdx.x;
    if (b < nb_wqk) { dev_wqk(Wn, qn, kn, wqn, wkn, b, threadIdx.x); return; }
    int wid = ((b - nb_wqk) * 256 + threadIdx.x) >> 6;
    int lane = threadIdx.x & 63;
    if (wid >= n_nodes) return;
    const int l16 = lane & 15, g16 = lane >> 4;
    int r0 = rowptr[wid] + bsum[wid >> 10];
    int r1 = (wid + 1 < n_nodes) ? rowptr[wid + 1] + bsum[(wid + 1) >> 10] : ne;
    float acc[8] = {};
    float denom = 0.f;

    if (r1 > r0) {
        float sqv = (lane < N_REL) ? sq[lane * n_nodes + wid] : 0.f;

        for (int c0 = r0; c0 < r1; c0 += 64) {
            int j = c0 + lane;
            float ev = 0.f;
            int p = 0;
            if (j < r1) {
                p = pe[j];
                int s = p & 0xffff, t = p >> 16;
                float av = __shfl(sqv, t) + sk[t * n_nodes + s];
                av = av >= 0.f ? av : NEG_SLOPE * av;
                ev = __expf(fminf(av, 80.f));
            }
            float evs = ev;
            #pragma unroll
            for (int off = 32; off; off >>= 1) evs += __shfl_xor(evs, off);
            denom += evs;

            int C = r1 - c0;
            if (C > 64) C = 64;
            for (int jj = 0; jj < C; jj += 4) {
                int lsel = jj + g16;
                float evj = __shfl(ev, lsel);
                int pj = __shfl(p, lsel);
                int s = pj & 0xffff, t = pj >> 16;
                const unsigned char* row = XW + ((size_t)(t * n_nodes + s)) * CH + l16 * 8;
                uint2 v = *(const uint2*)row;
                f32x2 p0 = __builtin_amdgcn_cvt_pk_f32_fp8(v.x, false);
                f32x2 p1 = __builtin_amdgcn_cvt_pk_f32_fp8(v.x, true);
                f32x2 p2 = __builtin_amdgcn_cvt_pk_f32_fp8(v.y, false);
                f32x2 p3 = __builtin_amdgcn_cvt_pk_f32_fp8(v.y, true);
                acc[0] += evj * p0[0];
                acc[1] += evj * p0[1];
                acc[2] += evj * p1[0];
                acc[3] += evj * p1[1];
                acc[4] += evj * p2[0];
                acc[5] += evj * p2[1];
                acc[6] += evj * p3[0];
                acc[7] += evj * p3[1];
            }
        }
    }

    #pragma unroll
    for (int i = 0; i < 8; ++i) {
        acc[i] += __shfl_xor(acc[i], 16);
        acc[i] += __shfl_xor(acc[i], 32);
    }

    if (lane < 16) {
        float inv = denom > 0.f ? 1.f / denom : 0.f;
        unsigned pk[4];
        #pragma unroll
        for (int i = 0; i < 4; ++i) {
            float b0 = bias[l16 * 8 + 2 * i];
            float b1 = bias[l16 * 8 + 2 * i + 1];
            float o0 = acc[2 * i] * inv + b0;
            float o1 = acc[2 * i + 1] * inv + b1;
            o0 = o0 > 0.f ? o0 : 0.f;
            o1 = o1 > 0.f ? o1 : 0.f;
            pk[i] = (unsigned)f2bf(o0) | ((unsigned)f2bf(o1) << 16);
        }
        *(uint4*)(outb + (size_t)wid * CH + l16 * 8) = make_uint4(pk[0], pk[1], pk[2], pk[3]);
    }
}

// ================= tail =================

__global__ __launch_bounds__(256) void k_colsum(const unsigned short* __restrict__ h,
                                                float* __restrict__ sum, int n_nodes) {
    __shared__ float cs[CH];
    int tid = threadIdx.x;
    int c2 = (tid & 63) * 2;
    int rw = tid >> 6;
    if (tid < CH) cs[tid] = 0.f;
    __syncthreads();
    float a0 = 0.f, a1 = 0.f;
    for (int row = blockIdx.x * 4 + rw; row < n_nodes; row += gridDim.x * 4) {
        unsigned v = *(const unsigned*)(h + (size_t)row * CH + c2);
        a0 += __uint_as_float(v << 16);
        a1 += __uint_as_float(v & 0xffff0000u);
    }
    atomicAdd(&cs[c2], a0);
    atomicAdd(&cs[c2 + 1], a1);
    __syncthreads();
    if (tid < CH) atomicAdd(sum + tid, cs[tid]);
}

// ================= layer-2 W prep (wpack || qkpack) =================

__global__ __launch_bounds__(256) void k_wprep2(const float* __restrict__ W,
                                                unsigned short* __restrict__ Wpk,
                                                const float* __restrict__ wq,
                                                const float* __restrict__ wk,
                                                unsigned short* __restrict__ qkf) {
    int b = blockIdx.x, tid = threadIdx.x;
    if (b < 64) dev_wpack(W, Wpk, b * 256 + tid);
    else dev_qkpack(wq, wk, qkf, tid);
}

__global__ void k_head(const float* __restrict__ sum, const float* __restrict__ lw,
                       const float* __restrict__ lb, float* __restrict__ outp, int n_nodes) {
    __shared__ float mean[CH];
    int t = threadIdx.x;  // 128
    mean[t] = sum[t] / (float)n_nodes;
    __syncthreads();
    if (t < OUT_CH) {
        float g = lb[t];
        for (int i = 0; i < CH; ++i) g += mean[i] * lw[i * OUT_CH + t];
        float m = g;
        #pragma unroll
        for (int off = 8; off; off >>= 1) m = fmaxf(m, __shfl_xor(m, off, 16));
        float ex = expf(g - m);
        float se = ex;
        #pragma unroll
        for (int off = 8; off; off >>= 1) se += __shfl_xor(se, off, 16);
        outp[t] = g - m - logf(se);
    }
}

extern "C" void kernel_launch(void* const* d_in, const int* in_sizes, int n_in,
                              void* d_out, int out_size, void* d_ws, size_t ws_size,
                              hipStream_t stream) {
    const float* x  = (const float*)d_in[0];
    const float* W1 = (const float*)d_in[1];
    const float* q1 = (const float*)d_in[2];
    const float* k1 = (const float*)d_in[3];
    const float* b1 = (const float*)d_in[4];
    const float* W2 = (const float*)d_in[5];
    const float* q2 = (const float*)d_in[6];
    const float* k2 = (const float*)d_in[7];
    const float* b2 = (const float*)d_in[8];
    const float* lw = (const float*)d_in[9];
    const float* lb = (const float*)d_in[10];
    const int* ei   = (const int*)d_in[11];
    const int* etp  = (const int*)d_in[12];

    const int n  = in_sizes[0] / CH;
    const int ne = in_sizes[12];
    const int* esrc = ei;
    const int* edst = ei + ne;

    char* ws = (char*)d_ws;
    size_t off = 0;
    auto carve = [&](size_t bytes) -> char* {
        char* p = ws + off;
        off = (off + bytes + 255) & ~(size_t)255;
        return p;
    };
    unsigned char* xw   = (unsigned char*)carve((size_t)N_REL * n * CH);
    unsigned short* xb  = (unsigned short*)carve((size_t)n * CH * 2);
    unsigned short* h1b = (unsigned short*)carve((size_t)n * CH * 2);
    unsigned short* h2b = (unsigned short*)carve((size_t)n * CH * 2);
    unsigned short* wpk = (unsigned short*)carve((size_t)N_REL * 32 * 64 * 8 * 2);
    unsigned short* qkf = (unsigned short*)carve((size_t)256 * 8 * 2);
    float* sq     = (float*)carve((size_t)N_REL * n * 4);
    float* sk     = (float*)carve((size_t)N_REL * n * 4);
    float* wq     = (float*)carve(N_REL * CH * 4);
    float* wk     = (float*)carve(N_REL * CH * 4);
    int* count    = (int*)carve((size_t)n * 4);
    int* rowptr   = (int*)carve((size_t)(n + 1) * 4);
    int* rowptr_w = (int*)carve((size_t)n * 4);
    int* pe       = (int*)carve((size_t)ne * 4);
    int* bsum     = (int*)carve((size_t)256 * 4);
    int* total    = (int*)carve(4);
    float* sum128 = (float*)carve(CH * 4);

    hipMemsetAsync(count, 0, (size_t)n * 4, stream);
    hipMemsetAsync(sum128, 0, CH * 4, stream);

    const int nbscan = (n + 1023) / 1024;
    const int nb_cast = (int)(((long)n * CH / 8 + 255) / 256);
    const int nb_hist = (ne + 255) / 256;
    const int NW = 2048;
    const int nb_gemm = NW / 4;                       // 512
    const int ntiles = (n + 15) >> 4;
    const int nb_sqsk = (ntiles + 3) / 4;             // 782
    const int nb_scat = (ne + 255) / 256;             // 2344
    const int nb_attn = (n + 3) / 4;                  // 12500

    // cast || hist
    k_cast_hist<<<nb_cast + nb_hist, 256, 0, stream>>>(x, xb, (long)n * CH, edst, count, ne, nb_cast);
    // scan1 (chunk-local rowptr + rowptr_work) || wqk(L1)
    k_scan1_wqk<<<nbscan + 4, 256, 0, stream>>>(count, rowptr, rowptr_w, bsum, n, nbscan,
                                                W1, q1, k1, wq, wk);
    // scan2 (bsum exclusive scan) || wpack(L1) || qkpack(L1)
    k_scan2_wprep<<<66, 256, 0, stream>>>(bsum, total, nbscan, W1, wpk, wq, wk, qkf);
    // layer 1: gemm || sqsk || scatter (scatter folds bsum at use)
    k_fat<<<nb_gemm + nb_sqsk + nb_scat, 256, 0, stream>>>(xb, wpk, qkf, xw, sq, sk, n, NW,
                                                           nb_gemm, nb_sqsk,
                                                           esrc, edst, etp, rowptr_w, bsum, pe, ne);
    // attn(L1) || wqk(L2)
    k_attn_wqk<<<4 + nb_attn, 256, 0, stream>>>(rowptr, bsum, pe, sq, sk, xw, b1, h1b, n, ne,
                                                W2, q2, k2, wq, wk, 4);
    // wpack(L2) || qkpack(L2)
    k_wprep2<<<65, 256, 0, stream>>>(W2, wpk, wq, wk, qkf);
    // layer 2: standalone gemm + sqsk (own regalloc -> W stays resident)
    k_gemm3<<<nb_gemm, 256, 0, stream>>>(h1b, wpk, xw, n, NW);
    k_sqsk2<<<(ntiles + 3) / 4, 256, 0, stream>>>(h1b, qkf, sq, sk, n);
    // attn(L2)
    k_attn_wqk<<<nb_attn, 256, 0, stream>>>(rowptr, bsum, pe, sq, sk, xw, b2, h2b, n, ne,
                                            (const float*)nullptr, (const float*)nullptr,
                                            (const float*)nullptr, (float*)nullptr,
                                            (float*)nullptr, 0);

    k_colsum<<<256, 256, 0, stream>>>(h2b, sum128, n);
    k_head<<<1, CH, 0, stream>>>(sum128, lw, lb, (float*)d_out, n);
}